// Round 1
// baseline (360.325 us; speedup 1.0000x reference)
//
#include <hip/hip_runtime.h>
#include <math.h>

// Problem dims (fixed by reference)
#define BD   4
#define TD   8
#define CD   32
#define WD   40
#define KD   9      // final top-k
#define HWD  1600
#define TM1  7      // T-1
#define K1   12     // phase-1 candidates kept (margin over 9 for f32 noise)

#define WAVES  4
#define CHUNK  400   // j-range per wave
#define TJ     50    // j per LDS tile
#define NTILE  8     // CHUNK / TJ
#define ROWF   36    // padded floats per LDS row (36*4=144 B, 16B-aligned rows)

#define OUTK ((size_t)BD * TM1 * HWD * KD)   // 403200

__global__ __launch_bounds__(256, 4)
void motion_graph_kernel(const float* __restrict__ x, float* __restrict__ out)
{
    __shared__ __align__(16) float s_tile[WAVES][TJ * ROWF];
    __shared__ float s_rsq[WAVES][TJ];
    __shared__ float s_mval[WAVES - 1][64][K1];
    __shared__ int   s_midx[WAVES - 1][64][K1];

    const int tid  = threadIdx.x;
    const int lane = tid & 63;
    const int w    = tid >> 6;
    const int i    = blockIdx.x * 64 + lane;   // source node, < 1600 always
    const int f    = blockIdx.y;               // b*7 + t
    const int b    = f / TM1;
    const int t    = f - b * TM1;

    const float* __restrict__ A  = x + (size_t)(b * TD + t) * CD * HWD;       // frame t
    const float* __restrict__ Bp = x + (size_t)(b * TD + t + 1) * CD * HWD;   // frame t+1

    // ---- own (source) feature, f32-normalized for phase 1 ----
    float fa[CD];
    float ss = 0.f;
#pragma unroll
    for (int c = 0; c < CD; ++c) {
        float v = A[c * HWD + i];
        fa[c] = v;
        ss += v * v;
    }
    float rn = 1.0f / sqrtf(ss + 1e-8f);
#pragma unroll
    for (int c = 0; c < CD; ++c) fa[c] *= rn;

    // ---- phase-1 per-chunk top-K1 (f32) ----
    float kv[K1];
    int   ki[K1];
#pragma unroll
    for (int k = 0; k < K1; ++k) { kv[k] = -3.0e38f; ki[k] = 0; }

    float* tile = s_tile[w];
    float* rsq  = s_rsq[w];
    const int j0 = w * CHUNK;

    for (int tt = 0; tt < NTILE; ++tt) {
        const int jb = j0 + tt * TJ;

        // stage raw rows [50 j][32 c] (coalesced global, ~4-way LDS write conflicts)
#pragma unroll
        for (int m = 0; m < (TJ * CD) / 64; ++m) {   // 25 elements/lane
            int e  = m * 64 + lane;
            int c  = e / TJ;
            int jj = e - c * TJ;
            tile[jj * ROWF + c] = Bp[c * HWD + jb + jj];
        }
        // per-row inverse norms (fold into dot instead of normalizing rows)
        if (lane < TJ) {
            float s2 = 0.f;
            const float* row = &tile[lane * ROWF];
#pragma unroll
            for (int c = 0; c < CD; ++c) { float v = row[c]; s2 += v * v; }
            rsq[lane] = 1.0f / sqrtf(s2 + 1e-8f);
        }
        // wave-private: compiler orders ds_write -> ds_read with lgkmcnt; no barrier needed

        for (int jj = 0; jj < TJ; ++jj) {
            const float4* row4 = (const float4*)&tile[jj * ROWF];  // uniform addr -> broadcast
            float a0 = 0.f, a1 = 0.f, a2 = 0.f, a3 = 0.f;
#pragma unroll
            for (int c4 = 0; c4 < CD / 4; ++c4) {
                float4 r = row4[c4];
                a0 = fmaf(r.x, fa[c4 * 4 + 0], a0);
                a1 = fmaf(r.y, fa[c4 * 4 + 1], a1);
                a2 = fmaf(r.z, fa[c4 * 4 + 2], a2);
                a3 = fmaf(r.w, fa[c4 * 4 + 3], a3);
            }
            float d = ((a0 + a1) + (a2 + a3)) * rsq[jj];
            if (d > kv[K1 - 1]) {            // rare path; strict > keeps lower idx on ties
                int j = jb + jj;
                bool bg[K1];
#pragma unroll
                for (int k = 0; k < K1; ++k) bg[k] = d > kv[k];
#pragma unroll
                for (int k = K1 - 1; k >= 1; --k) {
                    kv[k] = bg[k - 1] ? kv[k - 1] : (bg[k] ? d : kv[k]);
                    ki[k] = bg[k - 1] ? ki[k - 1] : (bg[k] ? j : ki[k]);
                }
                if (bg[0]) { kv[0] = d; ki[0] = j; }
            }
        }
    }

    // ---- cross-chunk merge (chunk order = ascending j => correct tie-break) ----
    __syncthreads();
    if (w > 0) {
#pragma unroll
        for (int k = 0; k < K1; ++k) {
            s_mval[w - 1][lane][k] = kv[k];
            s_midx[w - 1][lane][k] = ki[k];
        }
    }
    __syncthreads();
    if (w != 0) return;   // no barriers past this point

    for (int src = 0; src < WAVES - 1; ++src) {
#pragma unroll
        for (int r = 0; r < K1; ++r) {
            float d = s_mval[src][lane][r];
            int   j = s_midx[src][lane][r];
            if (d > kv[K1 - 1]) {
                bool bg[K1];
#pragma unroll
                for (int k = 0; k < K1; ++k) bg[k] = d > kv[k];
#pragma unroll
                for (int k = K1 - 1; k >= 1; --k) {
                    kv[k] = bg[k - 1] ? kv[k - 1] : (bg[k] ? d : kv[k]);
                    ki[k] = bg[k - 1] ? ki[k - 1] : (bg[k] ? j : ki[k]);
                }
                if (bg[0]) { kv[0] = d; ki[0] = j; }
            }
        }
    }

    // ---- phase-2: exact f64 re-rank of the K1 candidates ----
    float ar[CD];
    double ssa = 0.0;
#pragma unroll
    for (int c = 0; c < CD; ++c) {
        float v = A[c * HWD + i];
        ar[c] = v;
        ssa = fma((double)v, (double)v, ssa);
    }
    const double rna = 1.0 / sqrt(ssa + 1e-8);

    double fv[KD];
    int    fi[KD];
#pragma unroll
    for (int k = 0; k < KD; ++k) { fv[k] = -1.0e300; fi[k] = 0; }

    for (int r = 0; r < K1; ++r) {
        const int j = ki[r];
        double dot = 0.0, ssb = 0.0;
#pragma unroll
        for (int c = 0; c < CD; ++c) {
            double bv = (double)Bp[c * HWD + j];
            dot = fma((double)ar[c], bv, dot);
            ssb = fma(bv, bv, ssb);
        }
        double val = dot * rna * (1.0 / sqrt(ssb + 1e-8));
        if (val > fv[KD - 1]) {
            bool bg[KD];
#pragma unroll
            for (int k = 0; k < KD; ++k) bg[k] = val > fv[k];
#pragma unroll
            for (int k = KD - 1; k >= 1; --k) {
                fv[k] = bg[k - 1] ? fv[k - 1] : (bg[k] ? val : fv[k]);
                fi[k] = bg[k - 1] ? fi[k - 1] : (bg[k] ? j : fi[k]);
            }
            if (bg[0]) { fv[0] = val; fi[0] = j; }
        }
    }

    // ---- outputs ----
    double wsum = 0.0;
#pragma unroll
    for (int k = 0; k < KD; ++k) wsum += fv[k];
    const double winv = 1.0 / (wsum + 1e-8);

    const size_t base = ((size_t)f * HWD + i) * KD;
    float* out_w = out;
    float* out_i = out + OUTK;
    float* out_n = out + 2 * OUTK;
    const int sy = i / WD;
    const int sx = i - sy * WD;
#pragma unroll
    for (int k = 0; k < KD; ++k) {
        const int j  = fi[k];
        const int ty = j / WD;
        const int tx = j - ty * WD;
        out_w[base + k] = (float)(fv[k] * winv);
        out_i[base + k] = (float)j;
        out_n[(base + k) * 2 + 0] = (float)(ty - sy);
        out_n[(base + k) * 2 + 1] = (float)(tx - sx);
    }
}

extern "C" void kernel_launch(void* const* d_in, const int* in_sizes, int n_in,
                              void* d_out, int out_size, void* d_ws, size_t ws_size,
                              hipStream_t stream)
{
    const float* x = (const float*)d_in[0];
    float* out = (float*)d_out;
    dim3 grid(HWD / 64, BD * TM1);   // (25, 28)
    motion_graph_kernel<<<grid, 256, 0, stream>>>(x, out);
}

// Round 2
// 273.136 us; speedup vs baseline: 1.3192x; 1.3192x over previous
//
#include <hip/hip_runtime.h>
#include <math.h>

// Problem dims (fixed by reference)
#define BD   4
#define TD   8
#define CD   32
#define WD   40
#define KD   9       // final top-k
#define HWD  1600
#define TM1  7       // T-1
#define K1   12      // phase-1 candidates per lane (margin over 9 for bf16 noise)
#define NPAIR (BD * TM1)
#define OUTK ((size_t)NPAIR * HWD * KD)   // 403200

typedef __attribute__((ext_vector_type(8))) short short8;   // 8 bf16 (4 VGPRs)
typedef __attribute__((ext_vector_type(4))) float f32x4;

__device__ __forceinline__ uint f2bf(float f) {             // f32 -> bf16 bits (RNE)
    uint u = __float_as_uint(f);
    return (u + 0x7FFFu + ((u >> 16) & 1u)) >> 16;
}

// ---------------- kernel 1: normalize + cast to bf16, node-major [bt][node][32] ----
__global__ __launch_bounds__(256)
void norm_kernel(const float* __restrict__ x, uint* __restrict__ fnw)
{
    const int node = blockIdx.x * 256 + threadIdx.x;
    const int bt   = blockIdx.y;
    if (node >= HWD) return;
    const float* src = x + (size_t)bt * CD * HWD + node;
    float v[CD];
    float ss = 0.f;
#pragma unroll
    for (int c = 0; c < CD; ++c) { float a = src[(size_t)c * HWD]; v[c] = a; ss += a * a; }
    const float rn = 1.0f / sqrtf(ss + 1e-8f);
    uint4* dst = (uint4*)(fnw + (size_t)(bt * HWD + node) * 16);
#pragma unroll
    for (int q = 0; q < 4; ++q) {
        uint w0 = f2bf(v[8*q+0]*rn) | (f2bf(v[8*q+1]*rn) << 16);
        uint w1 = f2bf(v[8*q+2]*rn) | (f2bf(v[8*q+3]*rn) << 16);
        uint w2 = f2bf(v[8*q+4]*rn) | (f2bf(v[8*q+5]*rn) << 16);
        uint w3 = f2bf(v[8*q+6]*rn) | (f2bf(v[8*q+7]*rn) << 16);
        dst[q] = make_uint4(w0, w1, w2, w3);
    }
}

// sorted-descending insertion of packed u32 into 12-slot list (static indices only)
__device__ __forceinline__ void ins12(uint (&kv)[K1], uint u)
{
    if (u > kv[K1 - 1]) {
        bool bg[K1];
#pragma unroll
        for (int k = 0; k < K1; ++k) bg[k] = u > kv[k];
#pragma unroll
        for (int k = K1 - 1; k >= 1; --k)
            kv[k] = bg[k - 1] ? kv[k - 1] : (bg[k] ? u : kv[k]);
        if (bg[0]) kv[0] = u;
    }
}

// ---------------- kernel 2: MFMA phase-1 top-12 + f64 re-rank + merge + outputs ----
// wave = one 16-row i-block; lane: i = ib + (lane&15), j-subset = {j : (j>>2)&3 == lane>>4}
__global__ __launch_bounds__(256, 4)
void topk_kernel(const float* __restrict__ x, const uint* __restrict__ fnw,
                 float* __restrict__ out)
{
    const int tid  = threadIdx.x;
    const int lane = tid & 63;
    const int wid  = tid >> 6;
    const int li   = lane & 15;
    const int gr   = lane >> 4;          // 0..3
    const int f    = blockIdx.y;         // frame pair
    const int b    = f / TM1;
    const int t    = f - b * TM1;
    const int ib   = blockIdx.x * 64 + wid * 16;
    const int i    = ib + li;

    const uint* fA = fnw + (size_t)(b * TD + t)     * HWD * 16;   // frame t   (B operand)
    const uint* fB = fnw + (size_t)(b * TD + t + 1) * HWD * 16;   // frame t+1 (A operand)

    // B-operand fragment: my i-node, constant across the whole j-scan
    const short8 bF = *(const short8*)(fA + (size_t)i * 16 + gr * 4);

    uint kv[K1];
#pragma unroll
    for (int k = 0; k < K1; ++k) kv[k] = 0u;   // packed(-1) > 0, all slots fill

    const f32x4 z4 = {0.f, 0.f, 0.f, 0.f};

    // software pipeline: mfma(s) issued before insertion of tile s-1
    short8 aF = *(const short8*)(fB + (size_t)li * 16 + gr * 4);
    f32x4 accP = __builtin_amdgcn_mfma_f32_16x16x32_bf16(aF, bF, z4, 0, 0, 0);
    int jbP = 0;

    for (int s = 1; s < HWD / 16; ++s) {
        const short8 aN = *(const short8*)(fB + (size_t)(s * 16 + li) * 16 + gr * 4);
        const f32x4 accN = __builtin_amdgcn_mfma_f32_16x16x32_bf16(aN, bF, z4, 0, 0, 0);
        const int jinv = 2047 - jbP - 4 * gr;
#pragma unroll
        for (int r = 0; r < 4; ++r) {
            uint u = __float_as_uint(accP[r]);
            u ^= (uint)((int)u >> 31) | 0x80000000u;      // monotonic map
            u = (u & 0xFFFFF800u) | (uint)(jinv - r);     // low 11 bits: 2047-j (stable ties)
            ins12(kv, u);
        }
        accP = accN;
        jbP  = s * 16;
    }
    {
        const int jinv = 2047 - jbP - 4 * gr;
#pragma unroll
        for (int r = 0; r < 4; ++r) {
            uint u = __float_as_uint(accP[r]);
            u ^= (uint)((int)u >> 31) | 0x80000000u;
            u = (u & 0xFFFFF800u) | (uint)(jinv - r);
            ins12(kv, u);
        }
    }

    // ---- phase-2: exact f64 re-score of this lane's 12 candidates ----
    const float* Araw = x + (size_t)(b * TD + t)     * CD * HWD;
    const float* Braw = x + (size_t)(b * TD + t + 1) * CD * HWD;

    double ssa = 0.0;
#pragma unroll
    for (int c = 0; c < CD; ++c) {
        const double a = (double)Araw[(size_t)c * HWD + i];
        ssa = fma(a, a, ssa);
    }
    const double rna = 1.0 / sqrt(ssa + 1e-8);

    double fv[KD]; int fi[KD];
#pragma unroll
    for (int k = 0; k < KD; ++k) { fv[k] = -1.0e300; fi[k] = 0; }

#pragma unroll
    for (int r = 0; r < K1; ++r) {          // packed-desc order => stable tie order
        const int j = 2047 - (int)(kv[r] & 2047u);
        double dot = 0.0, ssb = 0.0;
#pragma unroll
        for (int c = 0; c < CD; ++c) {
            const double av = (double)Araw[(size_t)c * HWD + i];
            const double bv = (double)Braw[(size_t)c * HWD + j];
            dot = fma(av, bv, dot);
            ssb = fma(bv, bv, ssb);
        }
        const double val = dot * rna * (1.0 / sqrt(ssb + 1e-8));
        if (val > fv[KD - 1]) {
            bool bg[KD];
#pragma unroll
            for (int k = 0; k < KD; ++k) bg[k] = val > fv[k];
#pragma unroll
            for (int k = KD - 1; k >= 1; --k) {
                fv[k] = bg[k - 1] ? fv[k - 1] : (bg[k] ? val : fv[k]);
                fi[k] = bg[k - 1] ? fi[k - 1] : (bg[k] ? j : fi[k]);
            }
            if (bg[0]) { fv[0] = val; fi[0] = j; }
        }
    }

    // ---- 4-way sorted-list tournament merge across the i-group (lanes l^16, l^32) ----
    // j-coverage disjoint across group lanes => winner pops exactly one head
    double w9v[KD]; int w9j[KD];
#pragma unroll
    for (int rd = 0; rd < KD; ++rd) {
        double hv = fv[0]; int hj = fi[0];
        {
            const double ov = __shfl_xor(hv, 16); const int oj = __shfl_xor(hj, 16);
            const bool tk = (ov > hv) || (ov == hv && oj < hj);
            hv = tk ? ov : hv; hj = tk ? oj : hj;
        }
        {
            const double ov = __shfl_xor(hv, 32); const int oj = __shfl_xor(hj, 32);
            const bool tk = (ov > hv) || (ov == hv && oj < hj);
            hv = tk ? ov : hv; hj = tk ? oj : hj;
        }
        w9v[rd] = hv; w9j[rd] = hj;
        const bool win = (fi[0] == hj);   // head sentinels impossible within 9 rounds
#pragma unroll
        for (int k = 0; k < KD - 1; ++k) {
            fv[k] = win ? fv[k + 1] : fv[k];
            fi[k] = win ? fi[k + 1] : fi[k];
        }
        if (win) fv[KD - 1] = -1.0e300;
    }

    // ---- outputs: all 4 group lanes hold identical winners; split the stores ----
    double wsum = 0.0;
#pragma unroll
    for (int k = 0; k < KD; ++k) wsum += w9v[k];
    const double winv = 1.0 / (wsum + 1e-8);

    const size_t base = ((size_t)f * HWD + i) * KD;
    const int sy = i / WD, sx = i - sy * WD;
    if (gr == 0) {
#pragma unroll
        for (int k = 0; k < KD; ++k) out[base + k] = (float)(w9v[k] * winv);
    } else if (gr == 1) {
#pragma unroll
        for (int k = 0; k < KD; ++k) out[OUTK + base + k] = (float)w9j[k];
    } else if (gr == 2) {
#pragma unroll
        for (int k = 0; k < KD; ++k) {
            const int j = w9j[k];
            out[2 * OUTK + (base + k) * 2 + 0] = (float)(j / WD - sy);
        }
    } else {
#pragma unroll
        for (int k = 0; k < KD; ++k) {
            const int j = w9j[k];
            out[2 * OUTK + (base + k) * 2 + 1] = (float)(j - (j / WD) * WD - sx);
        }
    }
}

extern "C" void kernel_launch(void* const* d_in, const int* in_sizes, int n_in,
                              void* d_out, int out_size, void* d_ws, size_t ws_size,
                              hipStream_t stream)
{
    const float* x = (const float*)d_in[0];
    uint* fnw  = (uint*)d_ws;            // 4*8*1600*32 bf16 = 3.28 MB
    float* out = (float*)d_out;

    norm_kernel<<<dim3((HWD + 255) / 256, BD * TD), 256, 0, stream>>>(x, fnw);
    topk_kernel<<<dim3(HWD / 64, NPAIR), 256, 0, stream>>>(x, fnw, out);
}

// Round 3
// 172.220 us; speedup vs baseline: 2.0922x; 1.5860x over previous
//
#include <hip/hip_runtime.h>
#include <math.h>

// Problem dims (fixed by reference)
#define BD   4
#define TD   8
#define CD   32
#define WD   40
#define KD   9       // final top-k
#define HWD  1600
#define TM1  7       // T-1
#define K1   12      // phase-1 candidates per lane (margin over 9 for bf16 noise)
#define NPAIR (BD * TM1)
#define OUTK ((size_t)NPAIR * HWD * KD)   // 403200

// d_ws layout (bytes)
#define FNW_OFF   0                        // bf16 normalized, [bt][node][16 uints] = 3.2768 MB
#define TRAW_OFF  3276800                  // raw f32 node-major, [bt][node][32]   = 6.5536 MB
#define RND_OFF   9830400                  // f64 inv-norms, [bt][node]            = 0.4096 MB

typedef __attribute__((ext_vector_type(8))) short short8;   // 8 bf16 (4 VGPRs)
typedef __attribute__((ext_vector_type(4))) float f32x4;

__device__ __forceinline__ uint f2bf(float f) {             // f32 -> bf16 bits (RNE)
    uint u = __float_as_uint(f);
    return (u + 0x7FFFu + ((u >> 16) & 1u)) >> 16;
}

// ------- kernel 1: per-node normalize (bf16), raw transpose (f32), f64 norms -------
__global__ __launch_bounds__(256)
void prep_kernel(const float* __restrict__ x, uint* __restrict__ fnw,
                 float* __restrict__ traw, double* __restrict__ rnd)
{
    const int node = blockIdx.x * 256 + threadIdx.x;
    const int bt   = blockIdx.y;
    if (node >= HWD) return;
    const float* src = x + (size_t)bt * CD * HWD + node;
    float v[CD];
    float ss = 0.f;
    double ssd = 0.0;
#pragma unroll
    for (int c = 0; c < CD; ++c) {
        float a = src[(size_t)c * HWD];     // coalesced across threads
        v[c] = a;
        ss += a * a;
        ssd = fma((double)a, (double)a, ssd);
    }
    const float rn = 1.0f / sqrtf(ss + 1e-8f);
    rnd[(size_t)bt * HWD + node] = 1.0 / sqrt(ssd + 1e-8);

    uint4* dstb = (uint4*)(fnw + (size_t)(bt * HWD + node) * 16);
    float4* dstr = (float4*)(traw + (size_t)(bt * HWD + node) * 32);
#pragma unroll
    for (int q = 0; q < 4; ++q) {
        uint w0 = f2bf(v[8*q+0]*rn) | (f2bf(v[8*q+1]*rn) << 16);
        uint w1 = f2bf(v[8*q+2]*rn) | (f2bf(v[8*q+3]*rn) << 16);
        uint w2 = f2bf(v[8*q+4]*rn) | (f2bf(v[8*q+5]*rn) << 16);
        uint w3 = f2bf(v[8*q+6]*rn) | (f2bf(v[8*q+7]*rn) << 16);
        dstb[q] = make_uint4(w0, w1, w2, w3);
    }
#pragma unroll
    for (int q = 0; q < 8; ++q)
        dstr[q] = make_float4(v[4*q+0], v[4*q+1], v[4*q+2], v[4*q+3]);
}

// sorted-descending insertion of packed u32 into 12-slot list (static indices only)
__device__ __forceinline__ void ins12(uint (&kv)[K1], uint u)
{
    if (u > kv[K1 - 1]) {
        bool bg[K1];
#pragma unroll
        for (int k = 0; k < K1; ++k) bg[k] = u > kv[k];
#pragma unroll
        for (int k = K1 - 1; k >= 1; --k)
            kv[k] = bg[k - 1] ? kv[k - 1] : (bg[k] ? u : kv[k]);
        if (bg[0]) kv[0] = u;
    }
}

// ------- kernel 2: MFMA phase-1 top-12 + f64 re-rank + merge + outputs -------
// 1D grid of 700 blocks, XCD-bijective swizzle so each XCD owns ~3.5 frame pairs.
// wave = one 16-row i-block; lane: i = ib + (lane&15), j-subset {j : (j>>2)&3 == lane>>4}
__global__ __launch_bounds__(256)
void topk_kernel(const uint* __restrict__ fnw, const float* __restrict__ traw,
                 const double* __restrict__ rnd, float* __restrict__ out)
{
    const int tid  = threadIdx.x;
    const int lane = tid & 63;
    const int wid  = tid >> 6;
    const int li   = lane & 15;
    const int gr   = lane >> 4;          // 0..3

    // bijective XCD swizzle of 700 blocks: xcd 0..3 -> 88 works, xcd 4..7 -> 87
    const int bid  = blockIdx.x;
    const int xcd  = bid & 7;
    const int kk   = bid >> 3;
    const int work = (xcd < 4) ? (xcd * 88 + kk) : (352 + (xcd - 4) * 87 + kk);
    const int f    = work / 25;          // frame pair 0..27
    const int ibk  = work - f * 25;      // i-block 0..24
    const int b    = f / TM1;
    const int t    = f - b * TM1;
    const int bt0  = b * TD + t;
    const int bt1  = bt0 + 1;
    const int i    = ibk * 64 + wid * 16 + li;

    const uint* fA = fnw + (size_t)bt0 * HWD * 16;   // frame t   (B operand)
    const uint* fB = fnw + (size_t)bt1 * HWD * 16;   // frame t+1 (A operand)

    // B-operand fragment: my i-node, constant across the whole j-scan
    const short8 bF = *(const short8*)(fA + (size_t)i * 16 + gr * 4);

    uint kv[K1];
#pragma unroll
    for (int k = 0; k < K1; ++k) kv[k] = 0u;

    const f32x4 z4 = {0.f, 0.f, 0.f, 0.f};

    // software pipeline: mfma(s) issued before insertion of tile s-1
    short8 aF = *(const short8*)(fB + (size_t)li * 16 + gr * 4);
    f32x4 accP = __builtin_amdgcn_mfma_f32_16x16x32_bf16(aF, bF, z4, 0, 0, 0);
    int jbP = 0;

    for (int s = 1; s < HWD / 16; ++s) {
        const short8 aN = *(const short8*)(fB + (size_t)(s * 16 + li) * 16 + gr * 4);
        const f32x4 accN = __builtin_amdgcn_mfma_f32_16x16x32_bf16(aN, bF, z4, 0, 0, 0);
        const int jinv = 2047 - jbP - 4 * gr;
#pragma unroll
        for (int r = 0; r < 4; ++r) {
            uint u = __float_as_uint(accP[r]);
            u ^= (uint)((int)u >> 31) | 0x80000000u;      // monotonic map
            u = (u & 0xFFFFF800u) | (uint)(jinv - r);     // low 11 bits: 2047-j (stable ties)
            ins12(kv, u);
        }
        accP = accN;
        jbP  = s * 16;
    }
    {
        const int jinv = 2047 - jbP - 4 * gr;
#pragma unroll
        for (int r = 0; r < 4; ++r) {
            uint u = __float_as_uint(accP[r]);
            u ^= (uint)((int)u >> 31) | 0x80000000u;
            u = (u & 0xFFFFF800u) | (uint)(jinv - r);
            ins12(kv, u);
        }
    }

    // ---- phase-2: exact f64 re-score of this lane's 12 candidates ----
    // candidate rows are contiguous 128 B in node-major traw; norms precomputed in f64
    const float* tA = traw + (size_t)bt0 * HWD * 32 + (size_t)i * 32;
    float arf[CD];
#pragma unroll
    for (int q = 0; q < 8; ++q) {
        const float4 r4 = ((const float4*)tA)[q];
        arf[4*q+0] = r4.x; arf[4*q+1] = r4.y; arf[4*q+2] = r4.z; arf[4*q+3] = r4.w;
    }
    const double rna = rnd[(size_t)bt0 * HWD + i];
    const float*  trB = traw + (size_t)bt1 * HWD * 32;
    const double* rnB = rnd + (size_t)bt1 * HWD;

    double fv[KD]; int fi[KD];
#pragma unroll
    for (int k = 0; k < KD; ++k) { fv[k] = -1.0e300; fi[k] = 0; }

#pragma unroll
    for (int r = 0; r < K1; ++r) {          // packed-desc order => stable tie order
        const int j = 2047 - (int)(kv[r] & 2047u);
        const float4* rb = (const float4*)(trB + (size_t)j * 32);
        double dot = 0.0;
#pragma unroll
        for (int q = 0; q < 8; ++q) {
            const float4 r4 = rb[q];
            dot = fma((double)arf[4*q+0], (double)r4.x, dot);
            dot = fma((double)arf[4*q+1], (double)r4.y, dot);
            dot = fma((double)arf[4*q+2], (double)r4.z, dot);
            dot = fma((double)arf[4*q+3], (double)r4.w, dot);
        }
        const double val = dot * rna * rnB[j];
        if (val > fv[KD - 1]) {
            bool bg[KD];
#pragma unroll
            for (int k = 0; k < KD; ++k) bg[k] = val > fv[k];
#pragma unroll
            for (int k = KD - 1; k >= 1; --k) {
                fv[k] = bg[k - 1] ? fv[k - 1] : (bg[k] ? val : fv[k]);
                fi[k] = bg[k - 1] ? fi[k - 1] : (bg[k] ? j : fi[k]);
            }
            if (bg[0]) { fv[0] = val; fi[0] = j; }
        }
    }

    // ---- 4-way sorted-list tournament merge across the i-group (lanes l^16, l^32) ----
    // j-coverage disjoint across group lanes => winner pops exactly one head
    double w9v[KD]; int w9j[KD];
#pragma unroll
    for (int rd = 0; rd < KD; ++rd) {
        double hv = fv[0]; int hj = fi[0];
        {
            const double ov = __shfl_xor(hv, 16); const int oj = __shfl_xor(hj, 16);
            const bool tk = (ov > hv) || (ov == hv && oj < hj);
            hv = tk ? ov : hv; hj = tk ? oj : hj;
        }
        {
            const double ov = __shfl_xor(hv, 32); const int oj = __shfl_xor(hj, 32);
            const bool tk = (ov > hv) || (ov == hv && oj < hj);
            hv = tk ? ov : hv; hj = tk ? oj : hj;
        }
        w9v[rd] = hv; w9j[rd] = hj;
        const bool win = (fi[0] == hj);   // head sentinels impossible within 9 rounds
#pragma unroll
        for (int k = 0; k < KD - 1; ++k) {
            fv[k] = win ? fv[k + 1] : fv[k];
            fi[k] = win ? fi[k + 1] : fi[k];
        }
        if (win) fv[KD - 1] = -1.0e300;
    }

    // ---- outputs: all 4 group lanes hold identical winners; split the stores ----
    double wsum = 0.0;
#pragma unroll
    for (int k = 0; k < KD; ++k) wsum += w9v[k];
    const double winv = 1.0 / (wsum + 1e-8);

    const size_t base = ((size_t)f * HWD + i) * KD;
    const int sy = i / WD, sx = i - sy * WD;
    if (gr == 0) {
#pragma unroll
        for (int k = 0; k < KD; ++k) out[base + k] = (float)(w9v[k] * winv);
    } else if (gr == 1) {
#pragma unroll
        for (int k = 0; k < KD; ++k) out[OUTK + base + k] = (float)w9j[k];
    } else if (gr == 2) {
#pragma unroll
        for (int k = 0; k < KD; ++k) {
            const int j = w9j[k];
            out[2 * OUTK + (base + k) * 2 + 0] = (float)(j / WD - sy);
        }
    } else {
#pragma unroll
        for (int k = 0; k < KD; ++k) {
            const int j = w9j[k];
            out[2 * OUTK + (base + k) * 2 + 1] = (float)(j - (j / WD) * WD - sx);
        }
    }
}

extern "C" void kernel_launch(void* const* d_in, const int* in_sizes, int n_in,
                              void* d_out, int out_size, void* d_ws, size_t ws_size,
                              hipStream_t stream)
{
    const float* x = (const float*)d_in[0];
    uint*   fnw  = (uint*)((char*)d_ws + FNW_OFF);
    float*  traw = (float*)((char*)d_ws + TRAW_OFF);
    double* rnd  = (double*)((char*)d_ws + RND_OFF);
    float*  out  = (float*)d_out;

    prep_kernel<<<dim3((HWD + 255) / 256, BD * TD), 256, 0, stream>>>(x, fnw, traw, rnd);
    topk_kernel<<<dim3(NPAIR * 25), 256, 0, stream>>>(fnw, traw, rnd, out);
}

// Round 4
// 137.419 us; speedup vs baseline: 2.6221x; 1.2532x over previous
//
#include <hip/hip_runtime.h>
#include <math.h>

// Problem dims (fixed by reference)
#define BD   4
#define TD   8
#define CD   32
#define WD   40
#define KD   9       // final top-k
#define HWD  1600
#define TM1  7       // T-1
#define NPAIR (BD * TM1)
#define OUTK ((size_t)NPAIR * HWD * KD)   // 403200
#define CL   6       // per-class sorted-column length (4 columns per lane)
#define NEX  12      // candidates extracted per lane for f64 re-rank

// d_ws layout (bytes)
#define FNW_OFF   0                        // bf16 normalized, [bt][node][16 uints] = 3.2768 MB
#define TRAW_OFF  3276800                  // raw f32 node-major, [bt][node][32]   = 6.5536 MB
#define RND_OFF   9830400                  // f64 inv-norms, [bt][node]            = 0.4096 MB

typedef __attribute__((ext_vector_type(8))) short short8;   // 8 bf16 (4 VGPRs)
typedef __attribute__((ext_vector_type(4))) float f32x4;

__device__ __forceinline__ uint f2bf(float f) {             // f32 -> bf16 bits (RNE)
    uint u = __float_as_uint(f);
    return (u + 0x7FFFu + ((u >> 16) & 1u)) >> 16;
}

// ------- kernel 1: per-node normalize (bf16), raw transpose (f32), f64 norms -------
// 4 threads per (bt, node): thread q handles channels [8q, 8q+8)
__global__ __launch_bounds__(256)
void prep_kernel(const float* __restrict__ x, uint* __restrict__ fnw,
                 float* __restrict__ traw, double* __restrict__ rnd)
{
    const int gid  = blockIdx.x * 256 + threadIdx.x;   // 0 .. 204799
    const int q    = gid & 3;
    const int idx  = gid >> 2;                          // 0 .. 51199
    const int bt   = idx / HWD;
    const int node = idx - bt * HWD;

    const float* src = x + (size_t)bt * CD * HWD + node;
    float v[8];
    float ssq = 0.f;
    double ssd = 0.0;
#pragma unroll
    for (int cc = 0; cc < 8; ++cc) {
        const float a = src[(size_t)(q * 8 + cc) * HWD];
        v[cc] = a;
        ssq += a * a;
        ssd = fma((double)a, (double)a, ssd);
    }
    // 4-lane reduce (lanes 4k..4k+3 share a node)
    ssq += __shfl_xor(ssq, 1);  ssq += __shfl_xor(ssq, 2);
    ssd += __shfl_xor(ssd, 1);  ssd += __shfl_xor(ssd, 2);

    const float rn = 1.0f / sqrtf(ssq + 1e-8f);
    if (q == 0) rnd[(size_t)bt * HWD + node] = 1.0 / sqrt(ssd + 1e-8);

    uint* dstb = fnw + (size_t)(bt * HWD + node) * 16 + q * 4;
    const uint w0 = f2bf(v[0]*rn) | (f2bf(v[1]*rn) << 16);
    const uint w1 = f2bf(v[2]*rn) | (f2bf(v[3]*rn) << 16);
    const uint w2 = f2bf(v[4]*rn) | (f2bf(v[5]*rn) << 16);
    const uint w3 = f2bf(v[6]*rn) | (f2bf(v[7]*rn) << 16);
    *(uint4*)dstb = make_uint4(w0, w1, w2, w3);

    float* dstr = traw + (size_t)(bt * HWD + node) * 32 + q * 8;
    ((float4*)dstr)[0] = make_float4(v[0], v[1], v[2], v[3]);
    ((float4*)dstr)[1] = make_float4(v[4], v[5], v[6], v[7]);
}

// ------- kernel 2: MFMA phase-1 (4 sorted columns) + f64 re-rank + merge + outputs ---
// wave = one 16-row i-block; lane: i = ib + (lane&15), j-subset {j : (j>>2)&3 == lane>>4}
// column r holds top-CL of class {j : j mod 16 == 4*gr + r} (100 j's), branch-free insert.
__global__ __launch_bounds__(256)
void topk_kernel(const uint* __restrict__ fnw, const float* __restrict__ traw,
                 const double* __restrict__ rnd, float* __restrict__ out)
{
    const int tid  = threadIdx.x;
    const int lane = tid & 63;
    const int wid  = tid >> 6;
    const int li   = lane & 15;
    const int gr   = lane >> 4;          // 0..3

    // bijective XCD swizzle of 700 blocks: xcd 0..3 -> 88 works, xcd 4..7 -> 87
    const int bid  = blockIdx.x;
    const int xcd  = bid & 7;
    const int kk   = bid >> 3;
    const int work = (xcd < 4) ? (xcd * 88 + kk) : (352 + (xcd - 4) * 87 + kk);
    const int f    = work / 25;          // frame pair 0..27
    const int ibk  = work - f * 25;      // i-block 0..24
    const int b    = f / TM1;
    const int t    = f - b * TM1;
    const int bt0  = b * TD + t;
    const int bt1  = bt0 + 1;
    const int i    = ibk * 64 + wid * 16 + li;

    const uint* fA = fnw + (size_t)bt0 * HWD * 16;   // frame t   (B operand)
    const uint* fB = fnw + (size_t)bt1 * HWD * 16;   // frame t+1 (A operand)

    // B-operand fragment: my i-node, constant across the whole j-scan
    const short8 bF = *(const short8*)(fA + (size_t)i * 16 + gr * 4);

    // 4 sorted-descending columns of CL packed u32; 0 = empty sentinel
    uint C[4][CL];
#pragma unroll
    for (int r = 0; r < 4; ++r)
#pragma unroll
        for (int k = 0; k < CL; ++k) C[r][k] = 0u;

    // per-slot inverted-index registers: jr[r] = 2047 - (jb + 4*gr + r)
    int jr[4];
#pragma unroll
    for (int r = 0; r < 4; ++r) jr[r] = 2047 - 4 * gr - r;

    const f32x4 one4 = {1.f, 1.f, 1.f, 1.f};   // C=1: acc = 1 + sim >= 0 -> uint-monotonic

    short8 aF = *(const short8*)(fB + (size_t)li * 16 + gr * 4);
    f32x4 accP = __builtin_amdgcn_mfma_f32_16x16x32_bf16(aF, bF, one4, 0, 0, 0);

    for (int s = 1; s < HWD / 16; ++s) {
        const short8 aN = *(const short8*)(fB + (size_t)(s * 16 + li) * 16 + gr * 4);
        const f32x4 accN = __builtin_amdgcn_mfma_f32_16x16x32_bf16(aN, bF, one4, 0, 0, 0);
#pragma unroll
        for (int r = 0; r < 4; ++r) {
            int ub = __float_as_int(accP[r]);
            ub = ub < 0 ? 0 : ub;                                  // v_max_i32 guard
            uint u = ((uint)ub & 0xFFFFF800u) | (uint)jr[r];       // v_and_or pack
            uint tv = u;                                           // branch-free insert
#pragma unroll
            for (int k = 0; k < CL; ++k) {
                const uint lo = min(C[r][k], tv);
                C[r][k] = max(C[r][k], tv);
                tv = lo;
            }
            jr[r] -= 16;
        }
        accP = accN;
    }
#pragma unroll
    for (int r = 0; r < 4; ++r) {
        int ub = __float_as_int(accP[r]);
        ub = ub < 0 ? 0 : ub;
        uint u = ((uint)ub & 0xFFFFF800u) | (uint)jr[r];
        uint tv = u;
#pragma unroll
        for (int k = 0; k < CL; ++k) {
            const uint lo = min(C[r][k], tv);
            C[r][k] = max(C[r][k], tv);
            tv = lo;
        }
    }

    // ---- phase-2: extract NEX candidates in descending packed order, f64 re-score ----
    const float* tA = traw + (size_t)bt0 * HWD * 32 + (size_t)i * 32;
    float arf[CD];
#pragma unroll
    for (int q = 0; q < 8; ++q) {
        const float4 r4 = ((const float4*)tA)[q];
        arf[4*q+0] = r4.x; arf[4*q+1] = r4.y; arf[4*q+2] = r4.z; arf[4*q+3] = r4.w;
    }
    const double rna = rnd[(size_t)bt0 * HWD + i];
    const float*  trB = traw + (size_t)bt1 * HWD * 32;
    const double* rnB = rnd + (size_t)bt1 * HWD;

    double fv[KD]; int fi[KD];
#pragma unroll
    for (int k = 0; k < KD; ++k) { fv[k] = -1.0e300; fi[k] = 0; }

    for (int rd = 0; rd < NEX; ++rd) {
        // max of 4 column heads (packed values are unique -> exactly one pop)
        const uint m = max(max(C[0][0], C[1][0]), max(C[2][0], C[3][0]));
#pragma unroll
        for (int r = 0; r < 4; ++r) {
            const bool e = (C[r][0] == m);
#pragma unroll
            for (int k = 0; k < CL - 1; ++k) C[r][k] = e ? C[r][k + 1] : C[r][k];
            C[r][CL - 1] = e ? 0u : C[r][CL - 1];
        }
        const int j = 2047 - (int)(m & 2047u);
        const float4* rb = (const float4*)(trB + (size_t)j * 32);
        double dot = 0.0;
#pragma unroll
        for (int q = 0; q < 8; ++q) {
            const float4 r4 = rb[q];
            dot = fma((double)arf[4*q+0], (double)r4.x, dot);
            dot = fma((double)arf[4*q+1], (double)r4.y, dot);
            dot = fma((double)arf[4*q+2], (double)r4.z, dot);
            dot = fma((double)arf[4*q+3], (double)r4.w, dot);
        }
        const double val = dot * rna * rnB[j];
        if (val > fv[KD - 1]) {          // desc packed order => stable tie order
            bool bg[KD];
#pragma unroll
            for (int k = 0; k < KD; ++k) bg[k] = val > fv[k];
#pragma unroll
            for (int k = KD - 1; k >= 1; --k) {
                fv[k] = bg[k - 1] ? fv[k - 1] : (bg[k] ? val : fv[k]);
                fi[k] = bg[k - 1] ? fi[k - 1] : (bg[k] ? j : fi[k]);
            }
            if (bg[0]) { fv[0] = val; fi[0] = j; }
        }
    }

    // ---- 4-way sorted-list tournament merge across the i-group (lanes l^16, l^32) ----
    // j-coverage disjoint across group lanes => winner pops exactly one head
    double w9v[KD]; int w9j[KD];
#pragma unroll
    for (int rd = 0; rd < KD; ++rd) {
        double hv = fv[0]; int hj = fi[0];
        {
            const double ov = __shfl_xor(hv, 16); const int oj = __shfl_xor(hj, 16);
            const bool tk = (ov > hv) || (ov == hv && oj < hj);
            hv = tk ? ov : hv; hj = tk ? oj : hj;
        }
        {
            const double ov = __shfl_xor(hv, 32); const int oj = __shfl_xor(hj, 32);
            const bool tk = (ov > hv) || (ov == hv && oj < hj);
            hv = tk ? ov : hv; hj = tk ? oj : hj;
        }
        w9v[rd] = hv; w9j[rd] = hj;
        const bool win = (fi[0] == hj);   // head sentinels impossible within 9 rounds
#pragma unroll
        for (int k = 0; k < KD - 1; ++k) {
            fv[k] = win ? fv[k + 1] : fv[k];
            fi[k] = win ? fi[k + 1] : fi[k];
        }
        if (win) fv[KD - 1] = -1.0e300;
    }

    // ---- outputs: all 4 group lanes hold identical winners; split the stores ----
    double wsum = 0.0;
#pragma unroll
    for (int k = 0; k < KD; ++k) wsum += w9v[k];
    const double winv = 1.0 / (wsum + 1e-8);

    const size_t base = ((size_t)f * HWD + i) * KD;
    const int sy = i / WD, sx = i - sy * WD;
    if (gr == 0) {
#pragma unroll
        for (int k = 0; k < KD; ++k) out[base + k] = (float)(w9v[k] * winv);
    } else if (gr == 1) {
#pragma unroll
        for (int k = 0; k < KD; ++k) out[OUTK + base + k] = (float)w9j[k];
    } else if (gr == 2) {
#pragma unroll
        for (int k = 0; k < KD; ++k) {
            const int j = w9j[k];
            out[2 * OUTK + (base + k) * 2 + 0] = (float)(j / WD - sy);
        }
    } else {
#pragma unroll
        for (int k = 0; k < KD; ++k) {
            const int j = w9j[k];
            out[2 * OUTK + (base + k) * 2 + 1] = (float)(j - (j / WD) * WD - sx);
        }
    }
}

extern "C" void kernel_launch(void* const* d_in, const int* in_sizes, int n_in,
                              void* d_out, int out_size, void* d_ws, size_t ws_size,
                              hipStream_t stream)
{
    const float* x = (const float*)d_in[0];
    uint*   fnw  = (uint*)((char*)d_ws + FNW_OFF);
    float*  traw = (float*)((char*)d_ws + TRAW_OFF);
    double* rnd  = (double*)((char*)d_ws + RND_OFF);
    float*  out  = (float*)d_out;

    prep_kernel<<<dim3((TD * BD * HWD * 4) / 256), 256, 0, stream>>>(x, fnw, traw, rnd);
    topk_kernel<<<dim3(NPAIR * 25), 256, 0, stream>>>(fnw, traw, rnd, out);
}

// Round 5
// 130.052 us; speedup vs baseline: 2.7706x; 1.0566x over previous
//
#include <hip/hip_runtime.h>
#include <math.h>

// Problem dims (fixed by reference)
#define BD   4
#define TD   8
#define CD   32
#define WD   40
#define KD   9       // final top-k
#define HWD  1600
#define TM1  7       // T-1
#define NPAIR (BD * TM1)
#define OUTK ((size_t)NPAIR * HWD * KD)   // 403200
#define CL   6       // per-class sorted-column length (4 columns per lane)
#define NEX  12      // candidates extracted per lane for f64 re-rank

// d_ws layout (bytes)
#define FNW_OFF   0                        // bf16 normalized, [bt][node][16 uints] = 3.2768 MB
#define TRAW_OFF  3276800                  // raw f32 node-major, [bt][node][32]   = 6.5536 MB
#define RND_OFF   9830400                  // f64 inv-norms, [bt][node]            = 0.4096 MB

typedef __attribute__((ext_vector_type(8))) short short8;   // 8 bf16 (4 VGPRs)
typedef __attribute__((ext_vector_type(4))) float f32x4;

__device__ __forceinline__ uint f2bf(float f) {             // f32 -> bf16 bits (RNE)
    uint u = __float_as_uint(f);
    return (u + 0x7FFFu + ((u >> 16) & 1u)) >> 16;
}

// ------- kernel 1: per-node normalize (bf16), raw transpose (f32), f64 norms -------
// 4 threads per (bt, node): thread q handles channels [8q, 8q+8)  (UNCHANGED from R4)
__global__ __launch_bounds__(256)
void prep_kernel(const float* __restrict__ x, uint* __restrict__ fnw,
                 float* __restrict__ traw, double* __restrict__ rnd)
{
    const int gid  = blockIdx.x * 256 + threadIdx.x;   // 0 .. 204799
    const int q    = gid & 3;
    const int idx  = gid >> 2;                          // 0 .. 51199
    const int bt   = idx / HWD;
    const int node = idx - bt * HWD;

    const float* src = x + (size_t)bt * CD * HWD + node;
    float v[8];
    float ssq = 0.f;
    double ssd = 0.0;
#pragma unroll
    for (int cc = 0; cc < 8; ++cc) {
        const float a = src[(size_t)(q * 8 + cc) * HWD];
        v[cc] = a;
        ssq += a * a;
        ssd = fma((double)a, (double)a, ssd);
    }
    // 4-lane reduce (lanes 4k..4k+3 share a node)
    ssq += __shfl_xor(ssq, 1);  ssq += __shfl_xor(ssq, 2);
    ssd += __shfl_xor(ssd, 1);  ssd += __shfl_xor(ssd, 2);

    const float rn = 1.0f / sqrtf(ssq + 1e-8f);
    if (q == 0) rnd[(size_t)bt * HWD + node] = 1.0 / sqrt(ssd + 1e-8);

    uint* dstb = fnw + (size_t)(bt * HWD + node) * 16 + q * 4;
    const uint w0 = f2bf(v[0]*rn) | (f2bf(v[1]*rn) << 16);
    const uint w1 = f2bf(v[2]*rn) | (f2bf(v[3]*rn) << 16);
    const uint w2 = f2bf(v[4]*rn) | (f2bf(v[5]*rn) << 16);
    const uint w3 = f2bf(v[6]*rn) | (f2bf(v[7]*rn) << 16);
    *(uint4*)dstb = make_uint4(w0, w1, w2, w3);

    float* dstr = traw + (size_t)(bt * HWD + node) * 32 + q * 8;
    ((float4*)dstr)[0] = make_float4(v[0], v[1], v[2], v[3]);
    ((float4*)dstr)[1] = make_float4(v[4], v[5], v[6], v[7]);
}

// ------- kernel 2: MFMA phase-1 (4 sorted columns) + f64 re-rank + merge + outputs ---
// wave = one 16-row i-block; lane: i = ib + (lane&15), j-subset {j : (j>>2)&3 == lane>>4}
// column r holds top-CL of class {j : j mod 16 == 4*gr + r}, branch-free insert.
// R5: 4-deep register-ring prefetch (load-to-use distance = 1 unrolled iteration
// = 4 tiles of insert work, covering L2 latency). Candidate arithmetic identical to R4.
__global__ __launch_bounds__(256)
void topk_kernel(const uint* __restrict__ fnw, const float* __restrict__ traw,
                 const double* __restrict__ rnd, float* __restrict__ out)
{
    const int tid  = threadIdx.x;
    const int lane = tid & 63;
    const int wid  = tid >> 6;
    const int li   = lane & 15;
    const int gr   = lane >> 4;          // 0..3

    // bijective XCD swizzle of 700 blocks: xcd 0..3 -> 88 works, xcd 4..7 -> 87
    const int bid  = blockIdx.x;
    const int xcd  = bid & 7;
    const int kk   = bid >> 3;
    const int work = (xcd < 4) ? (xcd * 88 + kk) : (352 + (xcd - 4) * 87 + kk);
    const int f    = work / 25;          // frame pair 0..27
    const int ibk  = work - f * 25;      // i-block 0..24
    const int b    = f / TM1;
    const int t    = f - b * TM1;
    const int bt0  = b * TD + t;
    const int bt1  = bt0 + 1;
    const int i    = ibk * 64 + wid * 16 + li;

    const uint* fA = fnw + (size_t)bt0 * HWD * 16;   // frame t   (B operand)
    const uint* fB = fnw + (size_t)bt1 * HWD * 16;   // frame t+1 (A operand)

    // B-operand fragment: my i-node, constant across the whole j-scan
    const short8 bF = *(const short8*)(fA + (size_t)i * 16 + gr * 4);

    // 4 sorted-descending columns of CL packed u32; 0 = empty sentinel
    uint C[4][CL];
#pragma unroll
    for (int r = 0; r < 4; ++r)
#pragma unroll
        for (int k = 0; k < CL; ++k) C[r][k] = 0u;

    // per-slot inverted-index registers: jr[r] = 2047 - (jb + 4*gr + r)
    int jr[4];
#pragma unroll
    for (int r = 0; r < 4; ++r) jr[r] = 2047 - 4 * gr - r;

    const f32x4 one4 = {1.f, 1.f, 1.f, 1.f};   // C=1: acc = 1 + sim >= 0 -> uint-monotonic

#define LDT(dst, s) dst = *(const short8*)(fB + (size_t)((s) * 16 + li) * 16 + gr * 4)

#define INSTILE(acc) do {                                              \
    _Pragma("unroll")                                                  \
    for (int r = 0; r < 4; ++r) {                                      \
        int ub = __float_as_int((acc)[r]);                             \
        ub = ub < 0 ? 0 : ub;                                          \
        uint u = ((uint)ub & 0xFFFFF800u) | (uint)jr[r];               \
        uint tv = u;                                                   \
        _Pragma("unroll")                                              \
        for (int k = 0; k < CL; ++k) {                                 \
            const uint lo = min(C[r][k], tv);                          \
            C[r][k] = max(C[r][k], tv);                                \
            tv = lo;                                                   \
        }                                                              \
        jr[r] -= 16;                                                   \
    }                                                                  \
} while (0)

    short8 a0, a1, a2, a3;
    LDT(a0, 0); LDT(a1, 1); LDT(a2, 2); LDT(a3, 3);

    // main loop: 24 iterations, tiles 0..95; loads run 4 tiles ahead
    for (int sb = 0; sb < 96; sb += 4) {
        f32x4 acc;
        acc = __builtin_amdgcn_mfma_f32_16x16x32_bf16(a0, bF, one4, 0, 0, 0);
        LDT(a0, sb + 4);
        INSTILE(acc);
        acc = __builtin_amdgcn_mfma_f32_16x16x32_bf16(a1, bF, one4, 0, 0, 0);
        LDT(a1, sb + 5);
        INSTILE(acc);
        acc = __builtin_amdgcn_mfma_f32_16x16x32_bf16(a2, bF, one4, 0, 0, 0);
        LDT(a2, sb + 6);
        INSTILE(acc);
        acc = __builtin_amdgcn_mfma_f32_16x16x32_bf16(a3, bF, one4, 0, 0, 0);
        LDT(a3, sb + 7);
        INSTILE(acc);
    }
    // tail: tiles 96..99 (already loaded)
    {
        f32x4 acc;
        acc = __builtin_amdgcn_mfma_f32_16x16x32_bf16(a0, bF, one4, 0, 0, 0);
        INSTILE(acc);
        acc = __builtin_amdgcn_mfma_f32_16x16x32_bf16(a1, bF, one4, 0, 0, 0);
        INSTILE(acc);
        acc = __builtin_amdgcn_mfma_f32_16x16x32_bf16(a2, bF, one4, 0, 0, 0);
        INSTILE(acc);
        acc = __builtin_amdgcn_mfma_f32_16x16x32_bf16(a3, bF, one4, 0, 0, 0);
        INSTILE(acc);
    }
#undef LDT
#undef INSTILE

    // ---- phase-2: extract NEX candidates in descending packed order, f64 re-score ----
    const float* tA = traw + (size_t)bt0 * HWD * 32 + (size_t)i * 32;
    float arf[CD];
#pragma unroll
    for (int q = 0; q < 8; ++q) {
        const float4 r4 = ((const float4*)tA)[q];
        arf[4*q+0] = r4.x; arf[4*q+1] = r4.y; arf[4*q+2] = r4.z; arf[4*q+3] = r4.w;
    }
    const double rna = rnd[(size_t)bt0 * HWD + i];
    const float*  trB = traw + (size_t)bt1 * HWD * 32;
    const double* rnB = rnd + (size_t)bt1 * HWD;

    double fv[KD]; int fi[KD];
#pragma unroll
    for (int k = 0; k < KD; ++k) { fv[k] = -1.0e300; fi[k] = 0; }

    for (int rd = 0; rd < NEX; ++rd) {
        // max of 4 column heads (packed values are unique -> exactly one pop)
        const uint m = max(max(C[0][0], C[1][0]), max(C[2][0], C[3][0]));
#pragma unroll
        for (int r = 0; r < 4; ++r) {
            const bool e = (C[r][0] == m);
#pragma unroll
            for (int k = 0; k < CL - 1; ++k) C[r][k] = e ? C[r][k + 1] : C[r][k];
            C[r][CL - 1] = e ? 0u : C[r][CL - 1];
        }
        const int j = 2047 - (int)(m & 2047u);
        const float4* rb = (const float4*)(trB + (size_t)j * 32);
        double dot = 0.0;
#pragma unroll
        for (int q = 0; q < 8; ++q) {
            const float4 r4 = rb[q];
            dot = fma((double)arf[4*q+0], (double)r4.x, dot);
            dot = fma((double)arf[4*q+1], (double)r4.y, dot);
            dot = fma((double)arf[4*q+2], (double)r4.z, dot);
            dot = fma((double)arf[4*q+3], (double)r4.w, dot);
        }
        const double val = dot * rna * rnB[j];
        if (val > fv[KD - 1]) {          // desc packed order => stable tie order
            bool bg[KD];
#pragma unroll
            for (int k = 0; k < KD; ++k) bg[k] = val > fv[k];
#pragma unroll
            for (int k = KD - 1; k >= 1; --k) {
                fv[k] = bg[k - 1] ? fv[k - 1] : (bg[k] ? val : fv[k]);
                fi[k] = bg[k - 1] ? fi[k - 1] : (bg[k] ? j : fi[k]);
            }
            if (bg[0]) { fv[0] = val; fi[0] = j; }
        }
    }

    // ---- 4-way sorted-list tournament merge across the i-group (lanes l^16, l^32) ----
    // j-coverage disjoint across group lanes => winner pops exactly one head
    double w9v[KD]; int w9j[KD];
#pragma unroll
    for (int rd = 0; rd < KD; ++rd) {
        double hv = fv[0]; int hj = fi[0];
        {
            const double ov = __shfl_xor(hv, 16); const int oj = __shfl_xor(hj, 16);
            const bool tk = (ov > hv) || (ov == hv && oj < hj);
            hv = tk ? ov : hv; hj = tk ? oj : hj;
        }
        {
            const double ov = __shfl_xor(hv, 32); const int oj = __shfl_xor(hj, 32);
            const bool tk = (ov > hv) || (ov == hv && oj < hj);
            hv = tk ? ov : hv; hj = tk ? oj : hj;
        }
        w9v[rd] = hv; w9j[rd] = hj;
        const bool win = (fi[0] == hj);   // head sentinels impossible within 9 rounds
#pragma unroll
        for (int k = 0; k < KD - 1; ++k) {
            fv[k] = win ? fv[k + 1] : fv[k];
            fi[k] = win ? fi[k + 1] : fi[k];
        }
        if (win) fv[KD - 1] = -1.0e300;
    }

    // ---- outputs: all 4 group lanes hold identical winners; split the stores ----
    double wsum = 0.0;
#pragma unroll
    for (int k = 0; k < KD; ++k) wsum += w9v[k];
    const double winv = 1.0 / (wsum + 1e-8);

    const size_t base = ((size_t)f * HWD + i) * KD;
    const int sy = i / WD, sx = i - sy * WD;
    if (gr == 0) {
#pragma unroll
        for (int k = 0; k < KD; ++k) out[base + k] = (float)(w9v[k] * winv);
    } else if (gr == 1) {
#pragma unroll
        for (int k = 0; k < KD; ++k) out[OUTK + base + k] = (float)w9j[k];
    } else if (gr == 2) {
#pragma unroll
        for (int k = 0; k < KD; ++k) {
            const int j = w9j[k];
            out[2 * OUTK + (base + k) * 2 + 0] = (float)(j / WD - sy);
        }
    } else {
#pragma unroll
        for (int k = 0; k < KD; ++k) {
            const int j = w9j[k];
            out[2 * OUTK + (base + k) * 2 + 1] = (float)(j - (j / WD) * WD - sx);
        }
    }
}

extern "C" void kernel_launch(void* const* d_in, const int* in_sizes, int n_in,
                              void* d_out, int out_size, void* d_ws, size_t ws_size,
                              hipStream_t stream)
{
    const float* x = (const float*)d_in[0];
    uint*   fnw  = (uint*)((char*)d_ws + FNW_OFF);
    float*  traw = (float*)((char*)d_ws + TRAW_OFF);
    double* rnd  = (double*)((char*)d_ws + RND_OFF);
    float*  out  = (float*)d_out;

    prep_kernel<<<dim3((TD * BD * HWD * 4) / 256), 256, 0, stream>>>(x, fnw, traw, rnd);
    topk_kernel<<<dim3(NPAIR * 25), 256, 0, stream>>>(fnw, traw, rnd, out);
}